// Round 8
// baseline (205.910 us; speedup 1.0000x reference)
//
#include <hip/hip_runtime.h>

// CSA bf16-MFMA pipeline v14. B=4 H=W=128 C=128 heads=4 K2=9, hd=32.
// Softmax moved from att to av: att is now a pure logits GEMM (no lg, no
// softmax, 2 barriers/h, 37.4 KB LDS -> 4 blk/CU, stage||store overlap),
// storing raw bf16 logits in the SAME q-major layout. av does a register
// pre-pass (sum exp over 9 q-planes per item -> 8 inv regs) and applies
// exp*inv at the aLs scatter. No max-sub needed (|logit*scale| < ~0.3).
// av fold/V-MFMA/proj + cvt unchanged from v11/v13.
// ws: lgb[q*4+h][65536][5dw bf16-pairs] | wqb(linear) | wvb2 | wpb2

typedef short bf16x8 __attribute__((ext_vector_type(8)));
typedef float f32x4  __attribute__((ext_vector_type(4)));
typedef float v2f    __attribute__((ext_vector_type(2)));

#define SCALE 0.17677669529663687f   // hd^-0.5

__device__ __forceinline__ unsigned short f2bf(float f) {   // RNE
  unsigned u = __float_as_uint(f);
  u = (u + 0x7fffu + ((u >> 16) & 1u)) >> 16;
  return (unsigned short)u;
}
__device__ __forceinline__ float bf2f(unsigned short s) {
  return __uint_as_float(((unsigned)s) << 16);
}
// pack two f32 -> bf16 pair (round half-up): 2 add + 1 v_perm
__device__ __forceinline__ unsigned pk2bf(float lo, float hi) {
  unsigned a = __float_as_uint(lo) + 0x8000u;
  unsigned b = __float_as_uint(hi) + 0x8000u;
  return __builtin_amdgcn_perm(b, a, 0x07060302u);  // [b.hi16 : a.hi16]
}
__device__ __forceinline__ bf16x8 ld16(const unsigned short* p) {   // 16B-aligned
  union { bf16x8 v; uint4 u; } r;
  r.u = *(const uint4*)p;
  return r.v;
}

// ---------------- K0: fp32 -> bf16 weight conversion + fragment permute ----
// wq: linear. wv -> wvb2[(((q*4+cg)*2+m)*4+kk)*64+l][8] (A-frag order).
// wp -> wpb2[((tn*4+kk)*64+l)][8] (B-frag order).
__global__ __launch_bounds__(256) void cvt_kernel(const float* __restrict__ wq,
                                                  const float* __restrict__ wv,
                                                  const float* __restrict__ wp,
                                                  unsigned short* __restrict__ wqb,
                                                  unsigned short* __restrict__ wvb2,
                                                  unsigned short* __restrict__ wpb2) {
  int i = blockIdx.x * 256 + threadIdx.x;
  if (i >= 30848) return;
  if (i < 10368) {                       // wq: 4 floats each, layout unchanged
    long off = (long)i * 4;
    float4 v = *(const float4*)(wq + off);
    ushort4 o;
    o.x = f2bf(v.x); o.y = f2bf(v.y); o.z = f2bf(v.z); o.w = f2bf(v.w);
    *(ushort4*)(wqb + off) = o;
    return;
  }
  const float* s;
  unsigned short* d;
  if (i < 28800) {                       // wv fragment permute: 18432 items x 8
    int it = i - 10368;
    int l = it & 63, mk = it >> 6;
    int kk = mk & 3, m = (mk >> 2) & 1, qcg = mk >> 3;   // qcg = q*4+cg
    int cg = qcg & 3, q = qcg >> 2;
    int chan = cg * 32 + m * 16 + (l & 15);
    int k0 = kk * 32 + (l >> 4) * 8;
    s = wv + (long)q * 16384 + chan * 128 + k0;
    d = wvb2 + (long)it * 8;
  } else {                               // wp fragment permute: 2048 items x 8
    int it = i - 28800;
    int l = it & 63, kk = (it >> 6) & 3, tn = it >> 8;
    int col = tn * 16 + (l & 15);
    int k0 = kk * 32 + (l >> 4) * 8;
    s = wp + (long)col * 128 + k0;
    d = wpb2 + (long)it * 8;
  }
  float4 a = *(const float4*)s, b = *(const float4*)(s + 4);
  ushort4 o0, o1;
  o0.x = f2bf(a.x); o0.y = f2bf(a.y); o0.z = f2bf(a.z); o0.w = f2bf(a.w);
  o1.x = f2bf(b.x); o1.y = f2bf(b.y); o1.z = f2bf(b.z); o1.w = f2bf(b.w);
  *(ushort4*)d = o0;
  *(ushort4*)(d + 4) = o1;
}

// ---------------- K1: lgb = x @ w_qkv^T (raw bf16 logits) ----------------
// Pure GEMM: af from global, Bl LDS-staged weights, attile LDS transpose for
// coalesced q-major store. 2 barriers/h; stage(h+1) overlaps store(h).
__global__ __launch_bounds__(512, 4) void att_kernel(const float* __restrict__ x,
                                                     const unsigned short* __restrict__ wqb,
                                                     unsigned* __restrict__ lgb) {
  __shared__ unsigned short Bl[96 * 136];   // 26.1 KB: weight tile for head h
  __shared__ unsigned short attile[5760];   // 11.25 KB: [64 rows][9 q][10]
  const int t = threadIdx.x;
  const long m0 = (long)blockIdx.x * 64;
  const int w = t >> 6, lane = t & 63, qd = lane >> 4, l15 = lane & 15;
  const int rw = w & 3, th = w >> 2;          // row-group / tn-half of this wave
  // store decomposition: 2880 dwords, hoisted
  int dsto[6], srco[6];
#pragma unroll
  for (int k = 0; k < 6; k++) {
    int i = t + k * 512;
    if (i < 2880) {
      int q = i / 320, rem = i - q * 320, n = rem / 5, j = rem - n * 5;
      dsto[k] = (int)(((size_t)(q * 4) * 65536 + m0 + n) * 5 + j);
      srco[k] = n * 45 + q * 5 + j;
    } else { dsto[k] = -1; srco[k] = 0; }
  }
  // attile write slots for the 12 acc values, hoisted
  int ati[3]; bool ok[3];
#pragma unroll
  for (int tn = 0; tn < 3; tn++) {
    int c = th * 48 + tn * 16 + l15;
    ok[tn] = c < 81;
    int p = c / 9, q9 = c - p * 9;
    ati[tn] = (rw * 16 + qd * 4) * 90 + q9 * 10 + p;
  }
  // af straight from global fp32 (x rows m0..m0+63, 64 B/lane)
  bf16x8 af[4];
  {
    const float* xr = x + (m0 + rw * 16 + l15) * 128 + qd * 8;
#pragma unroll
    for (int kk = 0; kk < 4; kk++) {
      float4 a = *(const float4*)(xr + kk * 32);
      float4 b = *(const float4*)(xr + kk * 32 + 4);
      union { uint4 u; bf16x8 v; } r;
      r.u = make_uint4(pk2bf(a.x, a.y), pk2bf(a.z, a.w),
                       pk2bf(b.x, b.y), pk2bf(b.z, b.w));
      af[kk] = r.v;
    }
  }
  unsigned* ATdw = (unsigned*)attile;

#define STAGE_BL(hh)                                                            \
  { _Pragma("unroll") for (int k = 0; k < 3; k++) {                             \
      int i = t + k * 512;                                                      \
      if (i < 1296) {                                                           \
        int row = i >> 4, seg = i & 15;                                         \
        const uint4 v = *(const uint4*)(wqb + (long)((hh) * 81 + row) * 128 +   \
                                        seg * 8);                               \
        *(uint4*)((unsigned*)Bl + row * 68 + seg * 4) = v;                      \
      }                                                                         \
    } }

  STAGE_BL(0)
  __syncthreads();
  for (int h = 0; h < 4; h++) {
    f32x4 acc[3] = {};
#pragma unroll
    for (int kk = 0; kk < 4; kk++)
#pragma unroll
      for (int tn = 0; tn < 3; tn++) {
        bf16x8 bf = ld16(Bl + ((th * 3 + tn) * 16 + l15) * 136 + kk * 32 + qd * 8);
        acc[tn] = __builtin_amdgcn_mfma_f32_16x16x32_bf16(af[kk], bf, acc[tn], 0, 0, 0);
      }
#pragma unroll
    for (int tn = 0; tn < 3; tn++)
      if (ok[tn])
#pragma unroll
        for (int r = 0; r < 4; r++)
          attile[ati[tn] + r * 90] = f2bf(acc[tn][r]);
    __syncthreads();                        // attile ready; Bl(h) consumed
    if (h < 3) STAGE_BL(h + 1)              // overlaps store
#pragma unroll
    for (int k = 0; k < 6; k++)
      if (dsto[k] >= 0)
        lgb[dsto[k] + h * 327680] = ATdw[srco[k]];
    __syncthreads();                        // Bl(h+1) ready; attile free
  }
}

// ---------------- K2: fused softmax + V-MFMA + fold + proj ----------------
__global__ __launch_bounds__(512, 4) void av_kernel(const float* __restrict__ x,
                                                    const unsigned short* __restrict__ wvb2,
                                                    const unsigned* __restrict__ lgb,
                                                    const unsigned short* __restrict__ wpb2,
                                                    float* __restrict__ out) {
  __shared__ unsigned short A[144 * 136];   // 39.2 KB : x halo 12x12 ; yb alias for proj
  __shared__ unsigned short S[100 * 136];   // 27.2 KB : V_q (channel shorts per loc row)
  __shared__ unsigned aLs[2400];            // 9.6 KB  : att [h][100][6 dw]
  const int t = threadIdx.x;
  const int bb = blockIdx.z;
  const int r0 = blockIdx.y * 8, c0 = blockIdx.x * 8;
  const int l15 = t & 15, qd = (t >> 4) & 3, wvi = t >> 6;   // wvi in 0..7
  const int lane = t & 63;
  const int cg = wvi & 3, lp = wvi >> 2;                     // 2-mtile chan-group / loc-half
  const int n = (wvi & 3) * 16 + l15, lr = n >> 3, lc = n & 7;
  const int g = (wvi >> 2) * 4 + qd, head = g >> 1;          // 16-chan group (fold)
  const long nb = (long)bb * 16384;
  unsigned* Sdw = (unsigned*)S;
  unsigned* Adw = (unsigned*)A;

  // V-phase B-operand row bases: tile = lp*4+i (lp=1 has 3 tiles), loc=tile*16+l15
  int xbI[4];
#pragma unroll
  for (int i = 0; i < 4; i++) {
    int tile = lp * 4 + i;
    int ml = tile < 7 ? tile * 16 + l15 : 0;          // 0..111
    xbI[i] = (ml / 10) * 12 + (ml % 10) + 13;
  }

  // lgb load/scatter decomposition, hoisted out of the q loop
  int aoff[4], aidx[4];
#pragma unroll
  for (int k = 0; k < 4; k++) {
    int i = t + k * 512;
    if (i < 2000) {
      int hh = i / 500, rem = i - hh * 500, row = rem / 5, j5 = rem - row * 5;
      int gr = r0 - 1 + row / 10, gc = c0 - 1 + row % 10;
      aidx[k] = hh * 600 + row * 6 + j5;
      aoff[k] = (gr >= 0 && gr < 128 && gc >= 0 && gc < 128)
                    ? (int)(((size_t)hh * 65536 + nb + gr * 128 + gc) * 5 + j5)
                    : -1;
    } else { aidx[k] = -1; aoff[k] = -1; }
  }

  // ---- softmax pre-pass: per item, sum exp over the 9 q-planes -> inv ----
  float is0[4], is1[4];
#pragma unroll
  for (int k = 0; k < 4; k++) {
    float s0 = 0.f, s1 = 0.f;
#pragma unroll
    for (int q9 = 0; q9 < 9; q9++) {
      unsigned dv = (aoff[k] >= 0) ? lgb[aoff[k] + q9 * 1310720] : 0u;
      s0 += __expf(__uint_as_float(dv << 16) * SCALE);
      s1 += __expf(__uint_as_float(dv & 0xffff0000u) * SCALE);
    }
    is0[k] = 1.f / s0; is1[k] = 1.f / s1;
  }

  // ---- stage x halo 12x12 fp32 -> bf16 : 144 rows x 32 segs = 4608 ----
#pragma unroll
  for (int k = 0; k < 9; k++) {
    int i = t + k * 512;
    int row = i >> 5, seg = i & 31;
    int gr = r0 - 2 + row / 12, gc = c0 - 2 + row % 12;
    float4 v = make_float4(0.f, 0.f, 0.f, 0.f);
    if (gr >= 0 && gr < 128 && gc >= 0 && gc < 128)
      v = *(const float4*)(x + (nb + gr * 128 + gc) * 128 + seg * 4);
    *(uint2*)(Adw + row * 68 + seg * 2) = make_uint2(pk2bf(v.x, v.y), pk2bf(v.z, v.w));
  }

  // w_v A-frags: coalesced per-lane fragment layout (see cvt)
  const unsigned short* pwv = wvb2 + cg * 4096 + lane * 8;

  v2f y2[8];
#pragma unroll
  for (int i = 0; i < 8; i++) y2[i] = (v2f){0.f, 0.f};

  unsigned avv[4];
  bf16x8 wvf[2][4];                         // [mtile][kk] : 32 chans of w_v

#define LOAD_A(qq)                                                              \
  { _Pragma("unroll") for (int k = 0; k < 4; k++)                               \
      avv[k] = (aoff[k] >= 0) ? lgb[aoff[k] + (qq) * 1310720] : 0u; }
#define LOAD_WV(qq)                                                             \
  { _Pragma("unroll") for (int m = 0; m < 2; m++)                               \
    _Pragma("unroll") for (int kk = 0; kk < 4; kk++)                            \
      wvf[m][kk] = *(const bf16x8*)(pwv + (size_t)(qq) * 16384 +                \
                                    (m * 4 + kk) * 512); }

  LOAD_A(0)
  LOAD_WV(0)

  for (int q = 0; q < 9; q++) {
    const int qoff = (q / 3) * 12 + (q % 3) - 13;
    __syncthreads();                        // fold(q-1) readers done

    // logits -> probabilities -> aLs [h][row][6dw]
#pragma unroll
    for (int k = 0; k < 4; k++)
      if (aidx[k] >= 0) {
        unsigned pv = 0;
        if (aoff[k] >= 0) {
          unsigned dv = avv[k];
          float plo = __expf(__uint_as_float(dv << 16) * SCALE) * is0[k];
          float phi = __expf(__uint_as_float(dv & 0xffff0000u) * SCALE) * is1[k];
          pv = pk2bf(plo, phi);
        }
        aLs[aidx[k]] = pv;
      }

    // ---- V_q^T via 16x16x32 MFMA: D[row=chan][col=loc] ----
    // wave = 32 chans (cg) x loc-half (lp); one B-read feeds 2 m-MFMAs
#pragma unroll
    for (int i = 0; i < 4; i++) {
      const int tile = lp * 4 + i;
      if (tile < 7) {                       // lp=1 covers tiles 4..6
        int xr = xbI[i] + qoff;
        xr = xr > 143 ? 143 : xr;           // pad locs (ml>=100) clamp
        bf16x8 bx[4];
#pragma unroll
        for (int kk = 0; kk < 4; kk++)
          bx[kk] = ld16(A + xr * 136 + kk * 32 + qd * 8);
        f32x4 acc[2];
#pragma unroll
        for (int m = 0; m < 2; m++) acc[m] = (f32x4){0.f, 0.f, 0.f, 0.f};
#pragma unroll
        for (int kk = 0; kk < 4; kk++)
#pragma unroll
          for (int m = 0; m < 2; m++)
            acc[m] = __builtin_amdgcn_mfma_f32_16x16x32_bf16(wvf[m][kk], bx[kk],
                                                             acc[m], 0, 0, 0);
        int loc = tile * 16 + l15;
        if (loc < 100) {
#pragma unroll
          for (int m = 0; m < 2; m++)       // chans cg*32+m*16+qd*4 .. +3
            *(uint2*)(Sdw + loc * 68 + cg * 16 + m * 8 + qd * 2) =
                make_uint2(pk2bf(acc[m][0], acc[m][1]),
                           pk2bf(acc[m][2], acc[m][3]));
        }
      }
    }
    __syncthreads();
    if (q < 8) { LOAD_A(q + 1) LOAD_WV(q + 1) }   // overlap with fold

    // ---- fold: y[n, c(g)] += att[n',head,p,q] * V_q[n'] ; 2 x b128 per p ----
    const unsigned short* aS = (const unsigned short*)aLs;
    const int mlb = lr * 10 + lc + 11;
#pragma unroll
    for (int p = 0; p < 9; p++) {
      const int ml = mlb + (1 - p / 3) * 10 + (1 - p % 3);
      const float a = bf2f(aS[head * 1200 + ml * 12 + p]);
      const v2f a2 = {a, a};
      const uint4* Sr = (const uint4*)(Sdw + ml * 68 + g * 8);
#pragma unroll
      for (int v4 = 0; v4 < 2; v4++) {
        const uint4 u = Sr[v4];
        v2f xv;
        const int yi = v4 * 4;
        xv.x = __uint_as_float(u.x << 16); xv.y = __uint_as_float(u.x & 0xffff0000u);
        y2[yi + 0] += a2 * xv;
        xv.x = __uint_as_float(u.y << 16); xv.y = __uint_as_float(u.y & 0xffff0000u);
        y2[yi + 1] += a2 * xv;
        xv.x = __uint_as_float(u.z << 16); xv.y = __uint_as_float(u.z & 0xffff0000u);
        y2[yi + 2] += a2 * xv;
        xv.x = __uint_as_float(u.w << 16); xv.y = __uint_as_float(u.w & 0xffff0000u);
        y2[yi + 3] += a2 * xv;
      }
    }
  }

  // ---- proj: out = y @ wp^T (yb aliases A) ----
  __syncthreads();
  unsigned short* yb = A;
  {
    uint4 pk[2];
#pragma unroll
    for (int v4 = 0; v4 < 2; v4++) {
      pk[v4].x = pk2bf(y2[v4 * 4 + 0].x, y2[v4 * 4 + 0].y);
      pk[v4].y = pk2bf(y2[v4 * 4 + 1].x, y2[v4 * 4 + 1].y);
      pk[v4].z = pk2bf(y2[v4 * 4 + 2].x, y2[v4 * 4 + 2].y);
      pk[v4].w = pk2bf(y2[v4 * 4 + 3].x, y2[v4 * 4 + 3].y);
    }
    uint4* dst = (uint4*)(Adw + n * 68 + g * 8);
    dst[0] = pk[0]; dst[1] = pk[1];
  }
  __syncthreads();
  f32x4 pacc[4] = {};
#pragma unroll
  for (int kk = 0; kk < 4; kk++) {
    bf16x8 afr = ld16(yb + ((wvi & 3) * 16 + l15) * 136 + kk * 32 + qd * 8);
#pragma unroll
    for (int tn = 0; tn < 4; tn++) {
      bf16x8 bfr = *(const bf16x8*)(wpb2 + (((wvi >> 2) * 4 + tn) * 4 + kk) * 512 +
                                    lane * 8);
      pacc[tn] = __builtin_amdgcn_mfma_f32_16x16x32_bf16(afr, bfr, pacc[tn], 0, 0, 0);
    }
  }
#pragma unroll
  for (int tn = 0; tn < 4; tn++)
#pragma unroll
    for (int r = 0; r < 4; r++) {
      int nl = (wvi & 3) * 16 + qd * 4 + r;
      int col = ((wvi >> 2) * 4 + tn) * 16 + l15;
      out[(nb + (r0 + (nl >> 3)) * 128 + (c0 + (nl & 7))) * 128 + col] = pacc[tn][r];
    }
}

extern "C" void kernel_launch(void* const* d_in, const int* in_sizes, int n_in,
                              void* d_out, int out_size, void* d_ws, size_t ws_size,
                              hipStream_t stream) {
  const float* x  = (const float*)d_in[0];
  const float* wq = (const float*)d_in[1];
  const float* wv = (const float*)d_in[2];
  const float* wp = (const float*)d_in[3];
  char* w = (char*)d_ws;
  unsigned*       lgb  = (unsigned*)w;                        // 47,185,920 B (logits)
  unsigned short* wqb  = (unsigned short*)(w + 47185920);     // 82,944 B (linear)
  unsigned short* wvb2 = wqb + 41472;                         // 294,912 B (frag)
  unsigned short* wpb2 = wvb2 + 147456;                       // 32,768 B (frag)

  cvt_kernel<<<121, 256, 0, stream>>>(wq, wv, wp, wqb, wvb2, wpb2);
  att_kernel<<<1024, 512, 0, stream>>>(x, wqb, lgb);
  dim3 g3(16, 16, 4);
  av_kernel<<<g3, 512, 0, stream>>>(x, wvb2, lgb, wpb2, (float*)d_out);
}

// Round 9
// 204.527 us; speedup vs baseline: 1.0068x; 1.0068x over previous
//
#include <hip/hip_runtime.h>

// CSA bf16-MFMA pipeline v15. B=4 H=W=128 C=128 heads=4 K2=9, hd=32.
// att_kernel + 47MB logits intermediate ELIMINATED: logits+softmax fused
// into av's prologue. wq pre-permuted into 27 c-tiles (9 supertiles x 3)
// so each lane's D-regs hold all 9 q of one (h,p) group -> in-lane softmax
// (no max-sub; validated v14). Probs stored bf16 in LDS P[100][36g][10q]
// (72.4 KB, loc stride 181 dw). Fold reads P directly (aLs gone).
// LDS 139 KB -> 1 block/CU (launch_bounds(512,2), 256-VGPR cap).
// V-MFMA / fold / proj phases unchanged from v11.
// ws: wq2(frag,110KB) | wvb2(frag) | wpb2(frag)   (no big intermediate!)

typedef short bf16x8 __attribute__((ext_vector_type(8)));
typedef float f32x4  __attribute__((ext_vector_type(4)));
typedef float v2f    __attribute__((ext_vector_type(2)));

#define SCALE 0.17677669529663687f   // hd^-0.5

__device__ __forceinline__ unsigned short f2bf(float f) {   // RNE
  unsigned u = __float_as_uint(f);
  u = (u + 0x7fffu + ((u >> 16) & 1u)) >> 16;
  return (unsigned short)u;
}
__device__ __forceinline__ float bf2f(unsigned short s) {
  return __uint_as_float(((unsigned)s) << 16);
}
// pack two f32 -> bf16 pair (round half-up): 2 add + 1 v_perm
__device__ __forceinline__ unsigned pk2bf(float lo, float hi) {
  unsigned a = __float_as_uint(lo) + 0x8000u;
  unsigned b = __float_as_uint(hi) + 0x8000u;
  return __builtin_amdgcn_perm(b, a, 0x07060302u);  // [b.hi16 : a.hi16]
}
__device__ __forceinline__ bf16x8 ld16(const unsigned short* p) {   // 16B-aligned
  union { bf16x8 v; uint4 u; } r;
  r.u = *(const uint4*)p;
  return r.v;
}

// ---------------- K0: fp32 -> bf16 weight conversion + fragment permute ----
// wq -> wq2[((ct*4+kk)*64+l)*8] A-frag order, ct = s*3+tile (27 tiles):
//   lane row16=l&15 -> qd4=row16>>2, r=row16&3; group g=s*4+qd4 (=h*9+p),
//   q=tile*4+r (<9 else zero); c = (g/9)*81 + (g%9)*9 + q; k=kk*32+(l>>4)*8+j.
// wv -> wvb2[(((q*4+cg)*2+m)*4+kk)*64+l][8] (A-frag). wp -> wpb2 (B-frag).
__global__ __launch_bounds__(256) void cvt_kernel(const float* __restrict__ wq,
                                                  const float* __restrict__ wv,
                                                  const float* __restrict__ wp,
                                                  unsigned short* __restrict__ wq2,
                                                  unsigned short* __restrict__ wvb2,
                                                  unsigned short* __restrict__ wpb2) {
  int i = blockIdx.x * 256 + threadIdx.x;
  if (i >= 27392) return;
  if (i < 6912) {                        // wq2 supertile A-frag permute
    int l = i & 63, rest = i >> 6;
    int kk = rest & 3, ct = rest >> 2;   // ct 0..26
    int s = ct / 3, tile = ct - s * 3;
    int row16 = l & 15, qd4 = row16 >> 2, r = row16 & 3;
    int g = s * 4 + qd4, q = tile * 4 + r;
    int k0 = kk * 32 + (l >> 4) * 8;
    unsigned short* d = wq2 + (long)i * 8;
    ushort4 o0 = make_ushort4(0, 0, 0, 0), o1 = make_ushort4(0, 0, 0, 0);
    if (q < 9) {
      int c = (g / 9) * 81 + (g % 9) * 9 + q;
      const float* sp = wq + (long)c * 128 + k0;
      float4 a = *(const float4*)sp, b = *(const float4*)(sp + 4);
      o0.x = f2bf(a.x); o0.y = f2bf(a.y); o0.z = f2bf(a.z); o0.w = f2bf(a.w);
      o1.x = f2bf(b.x); o1.y = f2bf(b.y); o1.z = f2bf(b.z); o1.w = f2bf(b.w);
    }
    *(ushort4*)d = o0;
    *(ushort4*)(d + 4) = o1;
    return;
  }
  const float* s;
  unsigned short* d;
  if (i < 25344) {                       // wv fragment permute: 18432 items x 8
    int it = i - 6912;
    int l = it & 63, mk = it >> 6;
    int kk = mk & 3, m = (mk >> 2) & 1, qcg = mk >> 3;   // qcg = q*4+cg
    int cg = qcg & 3, q = qcg >> 2;
    int chan = cg * 32 + m * 16 + (l & 15);
    int k0 = kk * 32 + (l >> 4) * 8;
    s = wv + (long)q * 16384 + chan * 128 + k0;
    d = wvb2 + (long)it * 8;
  } else {                               // wp fragment permute: 2048 items x 8
    int it = i - 25344;
    int l = it & 63, kk = (it >> 6) & 3, tn = it >> 8;
    int col = tn * 16 + (l & 15);
    int k0 = kk * 32 + (l >> 4) * 8;
    s = wp + (long)col * 128 + k0;
    d = wpb2 + (long)it * 8;
  }
  float4 a = *(const float4*)s, b = *(const float4*)(s + 4);
  ushort4 o0, o1;
  o0.x = f2bf(a.x); o0.y = f2bf(a.y); o0.z = f2bf(a.z); o0.w = f2bf(a.w);
  o1.x = f2bf(b.x); o1.y = f2bf(b.y); o1.z = f2bf(b.z); o1.w = f2bf(b.w);
  *(ushort4*)d = o0;
  *(ushort4*)(d + 4) = o1;
}

// ---------------- K1: fused logits+softmax + V-MFMA + fold + proj --------
__global__ __launch_bounds__(512, 2) void av_kernel(const float* __restrict__ x,
                                                    const unsigned short* __restrict__ wvb2,
                                                    const unsigned short* __restrict__ wq2,
                                                    const unsigned short* __restrict__ wpb2,
                                                    float* __restrict__ out) {
  __shared__ unsigned short A[144 * 136];   // 39.2 KB : x halo 12x12 ; yb alias for proj
  __shared__ unsigned short S[100 * 136];   // 27.2 KB : V_q (channel shorts per loc row)
  __shared__ unsigned P[18100];             // 72.4 KB : probs [100 loc][181dw: 36g x 5dw]
  const int t = threadIdx.x;
  const int bb = blockIdx.z;
  const int r0 = blockIdx.y * 8, c0 = blockIdx.x * 8;
  const int l15 = t & 15, qd = (t >> 4) & 3, wvi = t >> 6;   // wvi in 0..7
  const int lane = t & 63;
  const int cg = wvi & 3, lp = wvi >> 2;                     // 2-mtile chan-group / loc-half
  const int n = (wvi & 3) * 16 + l15, lr = n >> 3, lc = n & 7;
  const int g = (wvi >> 2) * 4 + qd, head = g >> 1;          // 16-chan group (fold)
  const long nb = (long)bb * 16384;
  unsigned* Sdw = (unsigned*)S;
  unsigned* Adw = (unsigned*)A;

  // V-phase B-operand row bases: tile = lp*4+i (lp=1 has 3 tiles), loc=tile*16+l15
  int xbI[4];
#pragma unroll
  for (int i = 0; i < 4; i++) {
    int tile = lp * 4 + i;
    int ml = tile < 7 ? tile * 16 + l15 : 0;          // 0..111
    xbI[i] = (ml / 10) * 12 + (ml % 10) + 13;
  }

  // ---- stage x halo 12x12 fp32 -> bf16 : 144 rows x 32 segs = 4608 ----
#pragma unroll
  for (int k = 0; k < 9; k++) {
    int i = t + k * 512;
    int row = i >> 5, seg = i & 31;
    int gr = r0 - 2 + row / 12, gc = c0 - 2 + row % 12;
    float4 v = make_float4(0.f, 0.f, 0.f, 0.f);
    if (gr >= 0 && gr < 128 && gc >= 0 && gc < 128)
      v = *(const float4*)(x + (nb + gr * 128 + gc) * 128 + seg * 4);
    *(uint2*)(Adw + row * 68 + seg * 2) = make_uint2(pk2bf(v.x, v.y), pk2bf(v.z, v.w));
  }
  __syncthreads();                          // A staged (logit phase reads A)

  // ---- logit + in-lane softmax phase: P[loc][gg=h*9+p][q] bf16 probs ----
  // 63 units = 9 supertiles x 7 loc-tiles; wave wvi: units wvi*8..+7.
  // Per unit: D[c][loc] = wq2_frag x x_frag; lane (qd,l15) holds the 9 q of
  // group gg = s*4+qd at loc = lt*16+l15 in ac[tile][r] (q = tile*4+r).
#pragma unroll
  for (int k8 = 0; k8 < 8; k8++) {
    const int u = wvi * 8 + k8;
    if (u < 63) {
      const int s9 = u / 7, lt = u - s9 * 7;
      const int loc = lt * 16 + l15;
      const int l10 = loc / 10, lm = loc - l10 * 10;
      int xr = (l10 + 1) * 12 + lm + 1;
      xr = xr > 143 ? 143 : xr;             // pad locs clamp
      bf16x8 bx[4];
#pragma unroll
      for (int kk = 0; kk < 4; kk++)
        bx[kk] = ld16(A + xr * 136 + kk * 32 + qd * 8);
      f32x4 ac[3];
#pragma unroll
      for (int tl = 0; tl < 3; tl++) ac[tl] = (f32x4){0.f, 0.f, 0.f, 0.f};
      const unsigned short* pq = wq2 + (size_t)s9 * 6144 + lane * 8;  // s9*12*512
#pragma unroll
      for (int tl = 0; tl < 3; tl++)
#pragma unroll
        for (int kk = 0; kk < 4; kk++) {
          bf16x8 aq = *(const bf16x8*)(pq + (tl * 4 + kk) * 512);
          ac[tl] = __builtin_amdgcn_mfma_f32_16x16x32_bf16(aq, bx[kk], ac[tl], 0, 0, 0);
        }
      const int gr = r0 - 1 + l10, gc = c0 - 1 + lm;
      float e[9], sm = 0.f;
#pragma unroll
      for (int q9 = 0; q9 < 9; q9++) {
        e[q9] = __expf(ac[q9 >> 2][q9 & 3] * SCALE);
        sm += e[q9];
      }
      float inv = (gr >= 0 && gr < 128 && gc >= 0 && gc < 128) ? 1.f / sm : 0.f;
      if (loc < 100) {
        unsigned* Pw = P + loc * 181 + (s9 * 4 + qd) * 5;
        Pw[0] = pk2bf(e[0] * inv, e[1] * inv);
        Pw[1] = pk2bf(e[2] * inv, e[3] * inv);
        Pw[2] = pk2bf(e[4] * inv, e[5] * inv);
        Pw[3] = pk2bf(e[6] * inv, e[7] * inv);
        Pw[4] = pk2bf(e[8] * inv, 0.f);
      }
    }
  }

  // w_v A-frags: coalesced per-lane fragment layout (see cvt)
  const unsigned short* pwv = wvb2 + cg * 4096 + lane * 8;

  v2f y2[8];
#pragma unroll
  for (int i = 0; i < 8; i++) y2[i] = (v2f){0.f, 0.f};

  bf16x8 wvf[2][4];                         // [mtile][kk] : 32 chans of w_v

#define LOAD_WV(qq)                                                             \
  { _Pragma("unroll") for (int m = 0; m < 2; m++)                               \
    _Pragma("unroll") for (int kk = 0; kk < 4; kk++)                            \
      wvf[m][kk] = *(const bf16x8*)(pwv + (size_t)(qq) * 16384 +                \
                                    (m * 4 + kk) * 512); }

  LOAD_WV(0)

  for (int q = 0; q < 9; q++) {
    const int qoff = (q / 3) * 12 + (q % 3) - 13;
    __syncthreads();                        // fold(q-1) readers done; P complete (q=0)

    // ---- V_q^T via 16x16x32 MFMA: D[row=chan][col=loc] ----
    // wave = 32 chans (cg) x loc-half (lp); one B-read feeds 2 m-MFMAs
#pragma unroll
    for (int i = 0; i < 4; i++) {
      const int tile = lp * 4 + i;
      if (tile < 7) {                       // lp=1 covers tiles 4..6
        int xr = xbI[i] + qoff;
        xr = xr > 143 ? 143 : xr;           // pad locs (ml>=100) clamp
        bf16x8 bx[4];
#pragma unroll
        for (int kk = 0; kk < 4; kk++)
          bx[kk] = ld16(A + xr * 136 + kk * 32 + qd * 8);
        f32x4 acc[2];
#pragma unroll
        for (int m = 0; m < 2; m++) acc[m] = (f32x4){0.f, 0.f, 0.f, 0.f};
#pragma unroll
        for (int kk = 0; kk < 4; kk++)
#pragma unroll
          for (int m = 0; m < 2; m++)
            acc[m] = __builtin_amdgcn_mfma_f32_16x16x32_bf16(wvf[m][kk], bx[kk],
                                                             acc[m], 0, 0, 0);
        int loc = tile * 16 + l15;
        if (loc < 100) {
#pragma unroll
          for (int m = 0; m < 2; m++)       // chans cg*32+m*16+qd*4 .. +3
            *(uint2*)(Sdw + loc * 68 + cg * 16 + m * 8 + qd * 2) =
                make_uint2(pk2bf(acc[m][0], acc[m][1]),
                           pk2bf(acc[m][2], acc[m][3]));
        }
      }
    }
    __syncthreads();                        // S ready
    if (q < 8) { LOAD_WV(q + 1) }           // overlap with fold

    // ---- fold: y[n, c(g)] += P[ml,head,p,q] * V_q[ml] ; 2 x b128 per p ----
    const unsigned short* Ps = (const unsigned short*)P;
    const int mlb = lr * 10 + lc + 11;
    const int hq = head * 90 + q;
#pragma unroll
    for (int p = 0; p < 9; p++) {
      const int ml = mlb + (1 - p / 3) * 10 + (1 - p % 3);
      const float a = bf2f(Ps[ml * 362 + hq + p * 10]);
      const v2f a2 = {a, a};
      const uint4* Sr = (const uint4*)(Sdw + ml * 68 + g * 8);
#pragma unroll
      for (int v4 = 0; v4 < 2; v4++) {
        const uint4 u = Sr[v4];
        v2f xv;
        const int yi = v4 * 4;
        xv.x = __uint_as_float(u.x << 16); xv.y = __uint_as_float(u.x & 0xffff0000u);
        y2[yi + 0] += a2 * xv;
        xv.x = __uint_as_float(u.y << 16); xv.y = __uint_as_float(u.y & 0xffff0000u);
        y2[yi + 1] += a2 * xv;
        xv.x = __uint_as_float(u.z << 16); xv.y = __uint_as_float(u.z & 0xffff0000u);
        y2[yi + 2] += a2 * xv;
        xv.x = __uint_as_float(u.w << 16); xv.y = __uint_as_float(u.w & 0xffff0000u);
        y2[yi + 3] += a2 * xv;
      }
    }
  }

  // ---- proj: out = y @ wp^T (yb aliases A) ----
  __syncthreads();
  unsigned short* yb = A;
  {
    uint4 pk[2];
#pragma unroll
    for (int v4 = 0; v4 < 2; v4++) {
      pk[v4].x = pk2bf(y2[v4 * 4 + 0].x, y2[v4 * 4 + 0].y);
      pk[v4].y = pk2bf(y2[v4 * 4 + 1].x, y2[v4 * 4 + 1].y);
      pk[v4].z = pk2bf(y2[v4 * 4 + 2].x, y2[v4 * 4 + 2].y);
      pk[v4].w = pk2bf(y2[v4 * 4 + 3].x, y2[v4 * 4 + 3].y);
    }
    uint4* dst = (uint4*)(Adw + n * 68 + g * 8);
    dst[0] = pk[0]; dst[1] = pk[1];
  }
  __syncthreads();
  f32x4 pacc[4] = {};
#pragma unroll
  for (int kk = 0; kk < 4; kk++) {
    bf16x8 afr = ld16(yb + ((wvi & 3) * 16 + l15) * 136 + kk * 32 + qd * 8);
#pragma unroll
    for (int tn = 0; tn < 4; tn++) {
      bf16x8 bfr = *(const bf16x8*)(wpb2 + (((wvi >> 2) * 4 + tn) * 4 + kk) * 512 +
                                    lane * 8);
      pacc[tn] = __builtin_amdgcn_mfma_f32_16x16x32_bf16(afr, bfr, pacc[tn], 0, 0, 0);
    }
  }
#pragma unroll
  for (int tn = 0; tn < 4; tn++)
#pragma unroll
    for (int r = 0; r < 4; r++) {
      int nl = (wvi & 3) * 16 + qd * 4 + r;
      int col = ((wvi >> 2) * 4 + tn) * 16 + l15;
      out[(nb + (r0 + (nl >> 3)) * 128 + (c0 + (nl & 7))) * 128 + col] = pacc[tn][r];
    }
}

extern "C" void kernel_launch(void* const* d_in, const int* in_sizes, int n_in,
                              void* d_out, int out_size, void* d_ws, size_t ws_size,
                              hipStream_t stream) {
  const float* x  = (const float*)d_in[0];
  const float* wq = (const float*)d_in[1];
  const float* wv = (const float*)d_in[2];
  const float* wp = (const float*)d_in[3];
  char* w = (char*)d_ws;
  unsigned short* wq2  = (unsigned short*)w;                  // 110,592 B (frag)
  unsigned short* wvb2 = wq2 + 55296;                         // 294,912 B (frag)
  unsigned short* wpb2 = wvb2 + 147456;                       // 32,768 B (frag)

  cvt_kernel<<<107, 256, 0, stream>>>(wq, wv, wp, wq2, wvb2, wpb2);
  dim3 g3(16, 16, 4);
  av_kernel<<<g3, 512, 0, stream>>>(x, wvb2, wq2, wpb2, (float*)d_out);
}

// Round 10
// 193.066 us; speedup vs baseline: 1.0665x; 1.0594x over previous
//
#include <hip/hip_runtime.h>

// CSA bf16-MFMA pipeline v16. B=4 H=W=128 C=128 heads=4 K2=9, hd=32.
// v15 (fully fused, no big intermediate) + P moved from 72KB LDS to regs:
// each lane keeps its 9 probs packed bf16 (pr[8][4]+pr8[4]+pga2[4]=40 VGPR);
// per q, only the q-th slice is scattered to Pq[36][104] LDS (7.5 KB).
// LDS 139->73.9 KB -> 2 blocks/CU (launch_bounds(512,4), 128-VGPR cap;
// reg demand ~124 -- WRITE_SIZE is the spill tripwire).
// cvt identical to v15 (verified). V/fold/proj phases identical to v11.
// ws: wq2(frag,110KB) | wvb2(frag) | wpb2(frag)

typedef short bf16x8 __attribute__((ext_vector_type(8)));
typedef float f32x4  __attribute__((ext_vector_type(4)));
typedef float v2f    __attribute__((ext_vector_type(2)));

#define SCALE 0.17677669529663687f   // hd^-0.5

__device__ __forceinline__ unsigned short f2bf(float f) {   // RNE
  unsigned u = __float_as_uint(f);
  u = (u + 0x7fffu + ((u >> 16) & 1u)) >> 16;
  return (unsigned short)u;
}
__device__ __forceinline__ float bf2f(unsigned short s) {
  return __uint_as_float(((unsigned)s) << 16);
}
// pack two f32 -> bf16 pair (round half-up): 2 add + 1 v_perm
__device__ __forceinline__ unsigned pk2bf(float lo, float hi) {
  unsigned a = __float_as_uint(lo) + 0x8000u;
  unsigned b = __float_as_uint(hi) + 0x8000u;
  return __builtin_amdgcn_perm(b, a, 0x07060302u);  // [b.hi16 : a.hi16]
}
__device__ __forceinline__ bf16x8 ld16(const unsigned short* p) {   // 16B-aligned
  union { bf16x8 v; uint4 u; } r;
  r.u = *(const uint4*)p;
  return r.v;
}

// ---------------- K0: fp32 -> bf16 weight conversion + fragment permute ----
// wq -> wq2[((ct*4+kk)*64+l)*8] A-frag order, ct = s*3+tile (27 tiles):
//   lane row16=l&15 -> qd4=row16>>2, r=row16&3; group g=s*4+qd4 (=h*9+p),
//   q=tile*4+r (<9 else zero); c = (g/9)*81 + (g%9)*9 + q; k=kk*32+(l>>4)*8+j.
// wv -> wvb2[(((q*4+cg)*2+m)*4+kk)*64+l][8] (A-frag). wp -> wpb2 (B-frag).
__global__ __launch_bounds__(256) void cvt_kernel(const float* __restrict__ wq,
                                                  const float* __restrict__ wv,
                                                  const float* __restrict__ wp,
                                                  unsigned short* __restrict__ wq2,
                                                  unsigned short* __restrict__ wvb2,
                                                  unsigned short* __restrict__ wpb2) {
  int i = blockIdx.x * 256 + threadIdx.x;
  if (i >= 27392) return;
  if (i < 6912) {                        // wq2 supertile A-frag permute
    int l = i & 63, rest = i >> 6;
    int kk = rest & 3, ct = rest >> 2;   // ct 0..26
    int s = ct / 3, tile = ct - s * 3;
    int row16 = l & 15, qd4 = row16 >> 2, r = row16 & 3;
    int g = s * 4 + qd4, q = tile * 4 + r;
    int k0 = kk * 32 + (l >> 4) * 8;
    unsigned short* d = wq2 + (long)i * 8;
    ushort4 o0 = make_ushort4(0, 0, 0, 0), o1 = make_ushort4(0, 0, 0, 0);
    if (q < 9) {
      int c = (g / 9) * 81 + (g % 9) * 9 + q;
      const float* sp = wq + (long)c * 128 + k0;
      float4 a = *(const float4*)sp, b = *(const float4*)(sp + 4);
      o0.x = f2bf(a.x); o0.y = f2bf(a.y); o0.z = f2bf(a.z); o0.w = f2bf(a.w);
      o1.x = f2bf(b.x); o1.y = f2bf(b.y); o1.z = f2bf(b.z); o1.w = f2bf(b.w);
    }
    *(ushort4*)d = o0;
    *(ushort4*)(d + 4) = o1;
    return;
  }
  const float* s;
  unsigned short* d;
  if (i < 25344) {                       // wv fragment permute: 18432 items x 8
    int it = i - 6912;
    int l = it & 63, mk = it >> 6;
    int kk = mk & 3, m = (mk >> 2) & 1, qcg = mk >> 3;   // qcg = q*4+cg
    int cg = qcg & 3, q = qcg >> 2;
    int chan = cg * 32 + m * 16 + (l & 15);
    int k0 = kk * 32 + (l >> 4) * 8;
    s = wv + (long)q * 16384 + chan * 128 + k0;
    d = wvb2 + (long)it * 8;
  } else {                               // wp fragment permute: 2048 items x 8
    int it = i - 25344;
    int l = it & 63, kk = (it >> 6) & 3, tn = it >> 8;
    int col = tn * 16 + (l & 15);
    int k0 = kk * 32 + (l >> 4) * 8;
    s = wp + (long)col * 128 + k0;
    d = wpb2 + (long)it * 8;
  }
  float4 a = *(const float4*)s, b = *(const float4*)(s + 4);
  ushort4 o0, o1;
  o0.x = f2bf(a.x); o0.y = f2bf(a.y); o0.z = f2bf(a.z); o0.w = f2bf(a.w);
  o1.x = f2bf(b.x); o1.y = f2bf(b.y); o1.z = f2bf(b.z); o1.w = f2bf(b.w);
  *(ushort4*)d = o0;
  *(ushort4*)(d + 4) = o1;
}

// ---------------- K1: fused logits+softmax + V-MFMA + fold + proj --------
__global__ __launch_bounds__(512, 4) void av_kernel(const float* __restrict__ x,
                                                    const unsigned short* __restrict__ wvb2,
                                                    const unsigned short* __restrict__ wq2,
                                                    const unsigned short* __restrict__ wpb2,
                                                    float* __restrict__ out) {
  __shared__ unsigned short A[144 * 136];   // 39.2 KB : x halo 12x12 ; yb alias for proj
  __shared__ unsigned short S[100 * 136];   // 27.2 KB : V_q (channel shorts per loc row)
  __shared__ unsigned short Pq[36 * 104];   // 7.5 KB  : probs slice [g=h*9+p][loc]
  const int t = threadIdx.x;
  const int bb = blockIdx.z;
  const int r0 = blockIdx.y * 8, c0 = blockIdx.x * 8;
  const int l15 = t & 15, qd = (t >> 4) & 3, wvi = t >> 6;   // wvi in 0..7
  const int lane = t & 63;
  const int cg = wvi & 3, lp = wvi >> 2;                     // 2-mtile chan-group / loc-half
  const int n = (wvi & 3) * 16 + l15, lr = n >> 3, lc = n & 7;
  const int g = (wvi >> 2) * 4 + qd, head = g >> 1;          // 16-chan group (fold)
  const long nb = (long)bb * 16384;
  unsigned* Sdw = (unsigned*)S;
  unsigned* Adw = (unsigned*)A;

  // V-phase B-operand row bases: tile = lp*4+i (lp=1 has 3 tiles), loc=tile*16+l15
  int xbI[4];
#pragma unroll
  for (int i = 0; i < 4; i++) {
    int tile = lp * 4 + i;
    int ml = tile < 7 ? tile * 16 + l15 : 0;          // 0..111
    xbI[i] = (ml / 10) * 12 + (ml % 10) + 13;
  }

  // ---- stage x halo 12x12 fp32 -> bf16 : 144 rows x 32 segs = 4608 ----
#pragma unroll
  for (int k = 0; k < 9; k++) {
    int i = t + k * 512;
    int row = i >> 5, seg = i & 31;
    int gr = r0 - 2 + row / 12, gc = c0 - 2 + row % 12;
    float4 v = make_float4(0.f, 0.f, 0.f, 0.f);
    if (gr >= 0 && gr < 128 && gc >= 0 && gc < 128)
      v = *(const float4*)(x + (nb + gr * 128 + gc) * 128 + seg * 4);
    *(uint2*)(Adw + row * 68 + seg * 2) = make_uint2(pk2bf(v.x, v.y), pk2bf(v.z, v.w));
  }
  __syncthreads();                          // A staged (logit phase reads A)

  // ---- logit + in-lane softmax phase -> packed prob registers ----
  // 63 units = 9 supertiles x 7 loc-tiles; wave wvi: units wvi*8..+7.
  // Lane (qd,l15) of unit u=(s9,lt) owns the 9 q of group g9=s9*4+qd at
  // loc=lt*16+l15. Probs bf16-packed: pr[k8][0..3] (q0..7), pr8 (q8 pairs).
  // pga2: packed Pq write addresses (0xFFFF = invalid).
  unsigned pr[8][4], pr8[4], pga2[4];
  {
    float prev_e8 = 0.f;
    unsigned short prev_a = 0xFFFFu;
#pragma unroll
    for (int k8 = 0; k8 < 8; k8++) {
      const int u = wvi * 8 + k8;
      unsigned short a16 = 0xFFFFu;
      float e8i = 0.f;
      if (u < 63) {
        const int s9 = u / 7, lt = u - s9 * 7;
        const int loc = lt * 16 + l15;
        const int l10 = loc / 10, lm = loc - l10 * 10;
        int xr = (l10 + 1) * 12 + lm + 1;
        xr = xr > 143 ? 143 : xr;             // pad locs clamp
        bf16x8 bx[4];
#pragma unroll
        for (int kk = 0; kk < 4; kk++)
          bx[kk] = ld16(A + xr * 136 + kk * 32 + qd * 8);
        f32x4 ac[3];
#pragma unroll
        for (int tl = 0; tl < 3; tl++) ac[tl] = (f32x4){0.f, 0.f, 0.f, 0.f};
        const unsigned short* pq = wq2 + (size_t)s9 * 6144 + lane * 8;
#pragma unroll
        for (int tl = 0; tl < 3; tl++)
#pragma unroll
          for (int kk = 0; kk < 4; kk++) {
            bf16x8 aq = *(const bf16x8*)(pq + (tl * 4 + kk) * 512);
            ac[tl] = __builtin_amdgcn_mfma_f32_16x16x32_bf16(aq, bx[kk], ac[tl], 0, 0, 0);
          }
        const int gr = r0 - 1 + l10, gc = c0 - 1 + lm;
        float e[9], sm = 0.f;
#pragma unroll
        for (int q9 = 0; q9 < 9; q9++) {
          e[q9] = __expf(ac[q9 >> 2][q9 & 3] * SCALE);
          sm += e[q9];
        }
        float inv = (gr >= 0 && gr < 128 && gc >= 0 && gc < 128) ? 1.f / sm : 0.f;
        pr[k8][0] = pk2bf(e[0] * inv, e[1] * inv);
        pr[k8][1] = pk2bf(e[2] * inv, e[3] * inv);
        pr[k8][2] = pk2bf(e[4] * inv, e[5] * inv);
        pr[k8][3] = pk2bf(e[6] * inv, e[7] * inv);
        e8i = e[8] * inv;
        if (loc < 100)
          a16 = (unsigned short)((s9 * 4 + qd) * 104 + loc);
      }
      if (k8 & 1) {
        pr8[k8 >> 1] = pk2bf(prev_e8, e8i);
        pga2[k8 >> 1] = (unsigned)prev_a | ((unsigned)a16 << 16);
      } else {
        prev_e8 = e8i;
        prev_a = a16;
      }
    }
  }

  // w_v A-frags: coalesced per-lane fragment layout (see cvt)
  const unsigned short* pwv = wvb2 + cg * 4096 + lane * 8;

  v2f y2[8];
#pragma unroll
  for (int i = 0; i < 8; i++) y2[i] = (v2f){0.f, 0.f};

  bf16x8 wvf[2][4];                         // [mtile][kk] : 32 chans of w_v

#define LOAD_WV(qq)                                                             \
  { _Pragma("unroll") for (int m = 0; m < 2; m++)                               \
    _Pragma("unroll") for (int kk = 0; kk < 4; kk++)                            \
      wvf[m][kk] = *(const bf16x8*)(pwv + (size_t)(qq) * 16384 +                \
                                    (m * 4 + kk) * 512); }

  LOAD_WV(0)

  for (int q = 0; q < 9; q++) {
    const int qoff = (q / 3) * 12 + (q % 3) - 13;
    __syncthreads();                        // fold(q-1) readers done (S, Pq free)

    // ---- scatter the q-th prob slice into Pq[g][loc] ----
#pragma unroll
    for (int k8 = 0; k8 < 8; k8++) {
      const unsigned a16 = (pga2[k8 >> 1] >> ((k8 & 1) * 16)) & 0xFFFFu;
      if (a16 != 0xFFFFu) {
        unsigned short v;
        if (q == 8) {
          v = (unsigned short)(pr8[k8 >> 1] >> ((k8 & 1) * 16));
        } else {
          unsigned dw = q < 2 ? pr[k8][0]
                      : (q < 4 ? pr[k8][1] : (q < 6 ? pr[k8][2] : pr[k8][3]));
          v = (q & 1) ? (unsigned short)(dw >> 16) : (unsigned short)dw;
        }
        Pq[a16] = v;
      }
    }

    // ---- V_q^T via 16x16x32 MFMA: D[row=chan][col=loc] ----
    // wave = 32 chans (cg) x loc-half (lp); one B-read feeds 2 m-MFMAs
#pragma unroll
    for (int i = 0; i < 4; i++) {
      const int tile = lp * 4 + i;
      if (tile < 7) {                       // lp=1 covers tiles 4..6
        int xr = xbI[i] + qoff;
        xr = xr > 143 ? 143 : xr;           // pad locs (ml>=100) clamp
        bf16x8 bx[4];
#pragma unroll
        for (int kk = 0; kk < 4; kk++)
          bx[kk] = ld16(A + xr * 136 + kk * 32 + qd * 8);
        f32x4 acc[2];
#pragma unroll
        for (int m = 0; m < 2; m++) acc[m] = (f32x4){0.f, 0.f, 0.f, 0.f};
#pragma unroll
        for (int kk = 0; kk < 4; kk++)
#pragma unroll
          for (int m = 0; m < 2; m++)
            acc[m] = __builtin_amdgcn_mfma_f32_16x16x32_bf16(wvf[m][kk], bx[kk],
                                                             acc[m], 0, 0, 0);
        int loc = tile * 16 + l15;
        if (loc < 100) {
#pragma unroll
          for (int m = 0; m < 2; m++)       // chans cg*32+m*16+qd*4 .. +3
            *(uint2*)(Sdw + loc * 68 + cg * 16 + m * 8 + qd * 2) =
                make_uint2(pk2bf(acc[m][0], acc[m][1]),
                           pk2bf(acc[m][2], acc[m][3]));
        }
      }
    }
    __syncthreads();                        // S + Pq ready
    if (q < 8) { LOAD_WV(q + 1) }           // overlap with fold

    // ---- fold: y[n, c(g)] += Pq[head*9+p][ml] * V_q[ml] ; 2 x b128 per p --
    const int mlb = lr * 10 + lc + 11;
    const int hb = head * 936;              // (head*9)*104
#pragma unroll
    for (int p = 0; p < 9; p++) {
      const int ml = mlb + (1 - p / 3) * 10 + (1 - p % 3);
      const float a = bf2f(Pq[hb + p * 104 + ml]);
      const v2f a2 = {a, a};
      const uint4* Sr = (const uint4*)(Sdw + ml * 68 + g * 8);
#pragma unroll
      for (int v4 = 0; v4 < 2; v4++) {
        const uint4 u = Sr[v4];
        v2f xv;
        const int yi = v4 * 4;
        xv.x = __uint_as_float(u.x << 16); xv.y = __uint_as_float(u.x & 0xffff0000u);
        y2[yi + 0] += a2 * xv;
        xv.x = __uint_as_float(u.y << 16); xv.y = __uint_as_float(u.y & 0xffff0000u);
        y2[yi + 1] += a2 * xv;
        xv.x = __uint_as_float(u.z << 16); xv.y = __uint_as_float(u.z & 0xffff0000u);
        y2[yi + 2] += a2 * xv;
        xv.x = __uint_as_float(u.w << 16); xv.y = __uint_as_float(u.w & 0xffff0000u);
        y2[yi + 3] += a2 * xv;
      }
    }
  }

  // ---- proj: out = y @ wp^T (yb aliases A) ----
  __syncthreads();
  unsigned short* yb = A;
  {
    uint4 pk[2];
#pragma unroll
    for (int v4 = 0; v4 < 2; v4++) {
      pk[v4].x = pk2bf(y2[v4 * 4 + 0].x, y2[v4 * 4 + 0].y);
      pk[v4].y = pk2bf(y2[v4 * 4 + 1].x, y2[v4 * 4 + 1].y);
      pk[v4].z = pk2bf(y2[v4 * 4 + 2].x, y2[v4 * 4 + 2].y);
      pk[v4].w = pk2bf(y2[v4 * 4 + 3].x, y2[v4 * 4 + 3].y);
    }
    uint4* dst = (uint4*)(Adw + n * 68 + g * 8);
    dst[0] = pk[0]; dst[1] = pk[1];
  }
  __syncthreads();
  f32x4 pacc[4] = {};
#pragma unroll
  for (int kk = 0; kk < 4; kk++) {
    bf16x8 afr = ld16(yb + ((wvi & 3) * 16 + l15) * 136 + kk * 32 + qd * 8);
#pragma unroll
    for (int tn = 0; tn < 4; tn++) {
      bf16x8 bfr = *(const bf16x8*)(wpb2 + (((wvi >> 2) * 4 + tn) * 4 + kk) * 512 +
                                    lane * 8);
      pacc[tn] = __builtin_amdgcn_mfma_f32_16x16x32_bf16(afr, bfr, pacc[tn], 0, 0, 0);
    }
  }
#pragma unroll
  for (int tn = 0; tn < 4; tn++)
#pragma unroll
    for (int r = 0; r < 4; r++) {
      int nl = (wvi & 3) * 16 + qd * 4 + r;
      int col = ((wvi >> 2) * 4 + tn) * 16 + l15;
      out[(nb + (r0 + (nl >> 3)) * 128 + (c0 + (nl & 7))) * 128 + col] = pacc[tn][r];
    }
}

extern "C" void kernel_launch(void* const* d_in, const int* in_sizes, int n_in,
                              void* d_out, int out_size, void* d_ws, size_t ws_size,
                              hipStream_t stream) {
  const float* x  = (const float*)d_in[0];
  const float* wq = (const float*)d_in[1];
  const float* wv = (const float*)d_in[2];
  const float* wp = (const float*)d_in[3];
  char* w = (char*)d_ws;
  unsigned short* wq2  = (unsigned short*)w;                  // 110,592 B (frag)
  unsigned short* wvb2 = wq2 + 55296;                         // 294,912 B (frag)
  unsigned short* wpb2 = wvb2 + 147456;                       // 32,768 B (frag)

  cvt_kernel<<<107, 256, 0, stream>>>(wq, wv, wp, wq2, wvb2, wpb2);
  dim3 g3(16, 16, 4);
  av_kernel<<<g3, 512, 0, stream>>>(x, wvb2, wq2, wpb2, (float*)d_out);
}